// Round 10
// baseline (472.852 us; speedup 1.0000x reference)
//
#include <hip/hip_runtime.h>

#define GN 4096
#define GF 128
#define GB 4

typedef __attribute__((ext_vector_type(8))) short short8;
typedef __attribute__((ext_vector_type(4))) float floatx4;

static __device__ __forceinline__ unsigned short f2bf(float x){
  unsigned int u = __float_as_uint(x);
  u += 0x7FFFu + ((u >> 16) & 1u);            // RNE
  return (unsigned short)(u >> 16);
}

// ---------- Kernel 0: bitpack adj (268MB stream -> 8.4MB bitmask) ----------
// 16384 independent waves, no barriers: saturates HBM.
__global__ __launch_bounds__(256)
void gat_pack(const int* __restrict__ adj, unsigned int* __restrict__ bits)
{
  const int lane = threadIdx.x & 63, wave = threadIdx.x >> 6;
  const size_t row = (size_t)blockIdx.x * 4 + wave;
  const int* src = adj + row * GN;
  unsigned long long* dst = (unsigned long long*)(bits + row * (GN/32));
  #pragma unroll 8
  for (int it = 0; it < GN/64; ++it){
    const int v = src[(it<<6) + lane];        // fully coalesced 256B/instr
    const unsigned long long m = __ballot(v > 0);
    if (lane == 0) dst[it] = m;
  }
}

// ---------- Kernel 1: Wh = h@W (f32), si, bf16 E/F tables, bf16 Wh fragment-major ----------
// whB layout: [b][jblk=j>>5][o][j&31] so a wave's B-fragment load is 1KB contiguous.
__global__ __launch_bounds__(256)
void gat_prep(const float* __restrict__ h, const float* __restrict__ W,
              const float* __restrict__ a, unsigned short* __restrict__ whB,
              float* __restrict__ si_g, unsigned short* __restrict__ EFh)
{
  __shared__ float hl[16*GF];                  // 8 KB
  __shared__ float red[2][2][16];
  const int tid = threadIdx.x;
  const int b   = blockIdx.x >> 8;
  const int r0  = (blockIdx.x & 255) << 4;
  const int o = tid & 127, g = tid >> 7;

  const float4* hb4 = (const float4*)(h + ((size_t)(b*GN + r0))*GF);
  ((float4*)hl)[tid]       = hb4[tid];
  ((float4*)hl)[tid + 256] = hb4[tid + 256];
  __syncthreads();

  float acc[8];
  #pragma unroll
  for (int r=0;r<8;++r) acc[r] = 0.f;
  const float* Wp = W + o;
  for (int f4=0; f4<32; ++f4){
    const float w0 = Wp[(f4*4+0)*GF];
    const float w1 = Wp[(f4*4+1)*GF];
    const float w2 = Wp[(f4*4+2)*GF];
    const float w3 = Wp[(f4*4+3)*GF];
    #pragma unroll
    for (int r=0;r<8;++r){
      const float4 h4 = *(const float4*)&hl[((g<<3)+r)*GF + (f4<<2)];
      acc[r] = fmaf(h4.x, w0, acc[r]);
      acc[r] = fmaf(h4.y, w1, acc[r]);
      acc[r] = fmaf(h4.z, w2, acc[r]);
      acc[r] = fmaf(h4.w, w3, acc[r]);
    }
  }

  const float ai = a[o], aj = a[GF + o];
  const int lane = tid & 63, wh = (tid >> 6) & 1;
  #pragma unroll
  for (int r=0;r<8;++r){
    float vi = acc[r]*ai, vj = acc[r]*aj;
    #pragma unroll
    for (int off=32; off; off>>=1){ vi += __shfl_down(vi, off); vj += __shfl_down(vj, off); }
    if (lane == 0){ red[0][wh][(g<<3)+r] = vi; red[1][wh][(g<<3)+r] = vj; }
  }

  // fragment-major bf16 store
  unsigned short us[8] __attribute__((aligned(16)));
  #pragma unroll
  for (int r=0;r<8;++r) us[r] = f2bf(acc[r]);
  {
    const int j0 = r0 + (g<<3);
    unsigned short* dst = whB + (((size_t)(b*128 + (j0>>5))*128 + o)<<5) + (j0&31);
    *(uint4*)dst = *(const uint4*)us;
  }

  __syncthreads();
  if (tid < 16){
    si_g[b*GN + r0 + tid] = red[0][0][tid] + red[0][1][tid];
  } else if (tid < 32){
    const int r = tid - 16;
    const float vsj = red[1][0][r] + red[1][1][r];
    EFh[(size_t)b*8192 + r0 + r]        = f2bf(__expf(vsj));
    EFh[(size_t)b*8192 + 4096 + r0 + r] = f2bf(__expf(0.2f*vsj));
  }
}

// ---------- Kernel 2: attention + PV via MFMA; bits pre-packed, pure compute ----------
__global__ __launch_bounds__(256, 2)
void gat_main(const unsigned int* __restrict__ adjbits, const unsigned short* __restrict__ whB,
              const float* __restrict__ si_g, const unsigned short* __restrict__ EFh,
              float* __restrict__ out)
{
  __shared__ __align__(16) char smem[(64*129 + 64)*4];              // 33.3 KB union
  unsigned short* sEj = (unsigned short*)smem;                      // [0,4096):E [4096,8192):F
  unsigned int*   bitsW  = (unsigned int*)(smem + 16384);           // [16][132]
  float* smemc = (float*)smem;                                      // combine (after K-loop)

  const int tid  = threadIdx.x;
  const int wave = tid >> 6, lane = tid & 63;
  const int b  = (blockIdx.x >> 1) & 3;
  const int i0 = ((((blockIdx.x >> 3) << 1) | (blockIdx.x & 1))) << 4;
  const int m = lane & 15, quad = lane >> 4, q8 = quad << 3;

  const int jw = wave << 10, jw32 = wave << 5;

  // --- stage EF (16KB) + bits (8KB) ---
  {
    const uint4* Eg = (const uint4*)(EFh + (size_t)b*8192);
    uint4* sE4 = (uint4*)sEj;
    #pragma unroll
    for (int k=0;k<4;++k) sE4[tid + (k<<8)] = Eg[tid + (k<<8)];
    const unsigned int* bg = adjbits + ((size_t)(b*GN + i0))*(GN/32);
    #pragma unroll
    for (int k=0;k<8;++k){
      const int idx = tid + (k<<8);              // 0..2047
      const int row = idx >> 7, w = idx & 127;
      bitsW[row*132 + w] = bg[(size_t)row*(GN/32) + w];
    }
  }
  __syncthreads();

  const float si_m = si_g[(size_t)b*GN + i0 + m];
  const float Ti = __expf(-si_m);              // es>0  <=>  Ej > Ti
  const float Ri = __expf(-0.8f*si_m);         // neg branch: Ri*Fj
  const unsigned short* lanebase = whB + ((size_t)b<<19) + (m<<5) + q8;

  floatx4 acc[8];
  #pragma unroll
  for (int c=0;c<8;++c) acc[c] = (floatx4){0.f,0.f,0.f,0.f};
  floatx4 lfrag = (floatx4){0.f,0.f,0.f,0.f};
  const short8 ones8 = {0x3F80,0x3F80,0x3F80,0x3F80,0x3F80,0x3F80,0x3F80,0x3F80};

  short8 Bcur[8], Bnxt[8];
  #pragma unroll
  for (int c=0;c<8;++c) Bcur[c] = *(const short8*)(lanebase + ((size_t)(jw32+0)<<12) + (c<<9));

  #pragma unroll 4
  for (int it = 0; it < 32; ++it){
    if (it < 31){
      const unsigned short* wn = lanebase + ((size_t)(jw32+it+1)<<12);
      #pragma unroll
      for (int c=0;c<8;++c) Bnxt[c] = *(const short8*)(wn + (c<<9));
    }
    const unsigned int sh = bitsW[m*132 + jw32 + it] >> q8;
    const int jj = jw + (it << 5) + q8;
    const short8 Es = *(const short8*)&sEj[jj];
    const short8 Fs = *(const short8*)&sEj[4096 + jj];
    const unsigned int* Eu = (const unsigned int*)&Es;
    const unsigned int* Fu = (const unsigned int*)&Fs;
    unsigned int aw[4];
    #pragma unroll
    for (int p=0;p<4;++p){
      unsigned int e0 = Eu[p] << 16, e1 = Eu[p] & 0xFFFF0000u;
      unsigned int f0 = Fu[p] << 16, f1 = Fu[p] & 0xFFFF0000u;
      float E0 = __uint_as_float(e0), E1 = __uint_as_float(e1);
      float t0 = Ri*__uint_as_float(f0), t1 = Ri*__uint_as_float(f1);
      float p0 = (E0 > Ti) ? E0 : t0;
      float p1 = (E1 > Ti) ? E1 : t1;
      unsigned int k0 = (unsigned int)(((int)(sh << (31-(2*p))))   >> 31);
      unsigned int k1 = (unsigned int)(((int)(sh << (31-(2*p+1)))) >> 31);
      unsigned int b0 = __float_as_uint(p0) & k0;
      unsigned int b1 = __float_as_uint(p1) & k1;
      aw[p] = ((b0 + 0x8000u) >> 16) | ((b1 + 0x8000u) & 0xFFFF0000u);
    }
    const short8 af = *(const short8*)aw;
    #pragma unroll
    for (int c=0;c<8;++c)
      acc[c] = __builtin_amdgcn_mfma_f32_16x16x32_bf16(af, Bcur[c], acc[c], 0, 0, 0);
    lfrag = __builtin_amdgcn_mfma_f32_16x16x32_bf16(af, ones8, lfrag, 0, 0, 0);
    #pragma unroll
    for (int c=0;c<8;++c) Bcur[c] = Bnxt[c];
  }

  // cross-wave combine (j-split partial sums)
  __syncthreads();
  #pragma unroll
  for (int c=0;c<8;++c){
    #pragma unroll
    for (int r=0;r<4;++r){
      smemc[(wave*16 + quad*4 + r)*129 + c*16 + m] = acc[c][r];
    }
  }
  if (m == 0){
    #pragma unroll
    for (int r=0;r<4;++r) smemc[8256 + wave*16 + quad*4 + r] = lfrag[r];
  }
  __syncthreads();

  #pragma unroll
  for (int k=0;k<8;++k){
    const int idx = tid + (k<<8);
    const int row = idx >> 7, col = idx & 127;
    const float s = smemc[row*129+col] + smemc[(16+row)*129+col]
                  + smemc[(32+row)*129+col] + smemc[(48+row)*129+col];
    const float l = smemc[8256+row] + smemc[8256+16+row]
                  + smemc[8256+32+row] + smemc[8256+48+row];
    float v = s / l;
    v = v > 0.f ? v : expm1f(v);               // ELU (alpha=1)
    out[((size_t)(b*GN + i0 + row))*GF + col] = v;
  }
}

extern "C" void kernel_launch(void* const* d_in, const int* in_sizes, int n_in,
                              void* d_out, int out_size, void* d_ws, size_t ws_size,
                              hipStream_t stream)
{
  (void)in_sizes; (void)n_in; (void)out_size; (void)ws_size;
  const float* h   = (const float*)d_in[0];
  const int*   adj = (const int*)d_in[1];
  const float* W   = (const float*)d_in[2];
  const float* a   = (const float*)d_in[3];
  float* out = (float*)d_out;

  char* ws = (char*)d_ws;
  unsigned short* whB   = (unsigned short*)ws;                    // 4 MB fragment-major
  float*          si    = (float*)(ws + (size_t)4*1024*1024);     // 64 KB
  unsigned short* EFh   = (unsigned short*)(ws + (size_t)4*1024*1024 + 64*1024);   // 64 KB
  unsigned int*   bits  = (unsigned int*)(ws + (size_t)4*1024*1024 + 128*1024);    // 8 MB

  gat_pack<<<(GB*GN)/4, 256, 0, stream>>>(adj, bits);
  gat_prep<<<GB*GN/16, 256, 0, stream>>>(h, W, a, whB, si, EFh);
  gat_main<<<GB*GN/16, 256, 0, stream>>>(bits, whB, si, EFh, out);
}

// Round 12
// 407.905 us; speedup vs baseline: 1.1592x; 1.1592x over previous
//
#include <hip/hip_runtime.h>

#define GN 4096
#define GF 128
#define GB 4

typedef __attribute__((ext_vector_type(8))) short short8;
typedef __attribute__((ext_vector_type(4))) float floatx4;

static __device__ __forceinline__ unsigned short f2bf(float x){
  unsigned int u = __float_as_uint(x);
  u += 0x7FFFu + ((u >> 16) & 1u);            // RNE
  return (unsigned short)(u >> 16);
}

// ---------- Kernel 1: Wh = h@W (f32), si, bf16 E/F tables, bf16 Wh fragment-major ----------
// whB layout: [b][jblk=j>>5][o][j&31] so a wave's B-fragment load is 1KB contiguous.
__global__ __launch_bounds__(256)
void gat_prep(const float* __restrict__ h, const float* __restrict__ W,
              const float* __restrict__ a, unsigned short* __restrict__ whB,
              float* __restrict__ si_g, unsigned short* __restrict__ EFh)
{
  __shared__ float hl[16*GF];                  // 8 KB
  __shared__ float red[2][2][16];
  const int tid = threadIdx.x;
  const int b   = blockIdx.x >> 8;
  const int r0  = (blockIdx.x & 255) << 4;
  const int o = tid & 127, g = tid >> 7;

  const float4* hb4 = (const float4*)(h + ((size_t)(b*GN + r0))*GF);
  ((float4*)hl)[tid]       = hb4[tid];
  ((float4*)hl)[tid + 256] = hb4[tid + 256];
  __syncthreads();

  float acc[8];
  #pragma unroll
  for (int r=0;r<8;++r) acc[r] = 0.f;
  const float* Wp = W + o;
  for (int f4=0; f4<32; ++f4){
    const float w0 = Wp[(f4*4+0)*GF];
    const float w1 = Wp[(f4*4+1)*GF];
    const float w2 = Wp[(f4*4+2)*GF];
    const float w3 = Wp[(f4*4+3)*GF];
    #pragma unroll
    for (int r=0;r<8;++r){
      const float4 h4 = *(const float4*)&hl[((g<<3)+r)*GF + (f4<<2)];
      acc[r] = fmaf(h4.x, w0, acc[r]);
      acc[r] = fmaf(h4.y, w1, acc[r]);
      acc[r] = fmaf(h4.z, w2, acc[r]);
      acc[r] = fmaf(h4.w, w3, acc[r]);
    }
  }

  const float ai = a[o], aj = a[GF + o];
  const int lane = tid & 63, wh = (tid >> 6) & 1;
  #pragma unroll
  for (int r=0;r<8;++r){
    float vi = acc[r]*ai, vj = acc[r]*aj;
    #pragma unroll
    for (int off=32; off; off>>=1){ vi += __shfl_down(vi, off); vj += __shfl_down(vj, off); }
    if (lane == 0){ red[0][wh][(g<<3)+r] = vi; red[1][wh][(g<<3)+r] = vj; }
  }

  // fragment-major bf16 store
  unsigned short us[8] __attribute__((aligned(16)));
  #pragma unroll
  for (int r=0;r<8;++r) us[r] = f2bf(acc[r]);
  {
    const int j0 = r0 + (g<<3);
    unsigned short* dst = whB + (((size_t)(b*128 + (j0>>5))*128 + o)<<5) + (j0&31);
    *(uint4*)dst = *(const uint4*)us;
  }

  __syncthreads();
  if (tid < 16){
    si_g[b*GN + r0 + tid] = red[0][0][tid] + red[0][1][tid];
  } else if (tid < 32){
    const int r = tid - 16;
    const float vsj = red[1][0][r] + red[1][1][r];
    EFh[(size_t)b*8192 + r0 + r]        = f2bf(__expf(vsj));
    EFh[(size_t)b*8192 + 4096 + r0 + r] = f2bf(__expf(0.2f*vsj));
  }
}

// ---------- Kernel 2: fused adj-pack + attention + PV; 32 i-rows/block ----------
// Each wave: 1024-j slice, TWO A-fragments (rows m, m+16) share one B octet ->
// B traffic halved, af-VALU doubled per iter covers B latency.
__global__ __launch_bounds__(256, 2)
void gat_main(const int* __restrict__ adj, const unsigned short* __restrict__ whB,
              const float* __restrict__ si_g, const unsigned short* __restrict__ EFh,
              float* __restrict__ out)
{
  __shared__ __align__(16) char smem[16384 + 32*134*4];             // 33.5 KB union
  unsigned short* sEj = (unsigned short*)smem;                      // [0,4096):E [4096,8192):F
  unsigned int*   bitsW  = (unsigned int*)(smem + 16384);           // [32][134]
  unsigned long long* bits64 = (unsigned long long*)(smem + 16384); // [32][67]
  float* smemc = (float*)smem;                                      // combine (after K-loop)

  const int tid  = threadIdx.x;
  const int wave = tid >> 6, lane = tid & 63;
  const int b  = (blockIdx.x >> 1) & 3;                             // XCD-pair per batch
  const int i0 = ((((blockIdx.x >> 3) << 1) | (blockIdx.x & 1))) << 5;
  const int m = lane & 15, quad = lane >> 4, q8 = quad << 3;

  const int jw = wave << 10, jw32 = wave << 5;

  // --- EF staging (16KB) ---
  {
    const uint4* Eg = (const uint4*)(EFh + (size_t)b*8192);
    uint4* sE4 = (uint4*)sEj;
    #pragma unroll
    for (int k=0;k<4;++k) sE4[tid + (k<<8)] = Eg[tid + (k<<8)];
  }

  // --- Phase 1: pack this block's adj tile (32 rows x this wave's 1024 j) ---
  // wave w emits 16 u64 words per row at word offset w*16  (stride 67 u64/row)
  {
    const int* adjb = adj + ((size_t)(b*GN + i0))*GN + jw;
    #pragma unroll 2
    for (int r = 0; r < 32; ++r){
      const int* src = adjb + (size_t)r*GN;
      int v[16];
      #pragma unroll
      for (int c = 0; c < 16; ++c)
        v[c] = __builtin_nontemporal_load(src + (c<<6) + lane);   // 256B/instr coalesced
      #pragma unroll
      for (int c = 0; c < 16; ++c){
        const unsigned long long mm = __ballot(v[c] > 0);
        if (lane == 0) bits64[r*67 + (wave<<4) + c] = mm;         // <<4 (16 words/wave)
      }
    }
  }
  __syncthreads();

  const float si0 = si_g[(size_t)b*GN + i0 + m];
  const float si1 = si_g[(size_t)b*GN + i0 + 16 + m];
  const float Ti0 = __expf(-si0),      Ti1 = __expf(-si1);
  const float Ri0 = __expf(-0.8f*si0), Ri1 = __expf(-0.8f*si1);
  const unsigned short* lanebase = whB + ((size_t)b<<19) + (m<<5) + q8;

  floatx4 acc0[8], acc1[8];
  #pragma unroll
  for (int c=0;c<8;++c){ acc0[c] = (floatx4){0.f,0.f,0.f,0.f}; acc1[c] = (floatx4){0.f,0.f,0.f,0.f}; }
  floatx4 lf0 = (floatx4){0.f,0.f,0.f,0.f}, lf1 = (floatx4){0.f,0.f,0.f,0.f};
  const short8 ones8 = {0x3F80,0x3F80,0x3F80,0x3F80,0x3F80,0x3F80,0x3F80,0x3F80};

#define MKAF(dst_, sh_, Ti_, Ri_) do { \
    unsigned int aw[4]; \
    _Pragma("unroll") \
    for (int p=0;p<4;++p){ \
      unsigned int e0 = Eu[p] << 16, e1 = Eu[p] & 0xFFFF0000u; \
      unsigned int f0 = Fu[p] << 16, f1 = Fu[p] & 0xFFFF0000u; \
      float E0 = __uint_as_float(e0), E1 = __uint_as_float(e1); \
      float t0 = (Ri_)*__uint_as_float(f0), t1 = (Ri_)*__uint_as_float(f1); \
      float p0 = (E0 > (Ti_)) ? E0 : t0; \
      float p1 = (E1 > (Ti_)) ? E1 : t1; \
      unsigned int k0 = (unsigned int)(((int)((sh_) << (31-(2*p))))   >> 31); \
      unsigned int k1 = (unsigned int)(((int)((sh_) << (31-(2*p+1)))) >> 31); \
      unsigned int b0 = __float_as_uint(p0) & k0; \
      unsigned int b1 = __float_as_uint(p1) & k1; \
      aw[p] = ((b0 + 0x8000u) >> 16) | ((b1 + 0x8000u) & 0xFFFF0000u); \
    } \
    dst_ = *(const short8*)aw; \
  } while(0)

  #pragma unroll 2
  for (int it = 0; it < 32; ++it){
    const unsigned short* wb = lanebase + ((size_t)(jw32+it)<<12);
    short8 Bc[8];
    #pragma unroll
    for (int c=0;c<8;++c) Bc[c] = *(const short8*)(wb + (c<<9));

    const unsigned int sh0 = bitsW[m*134 + jw32 + it] >> q8;
    const unsigned int sh1 = bitsW[(m+16)*134 + jw32 + it] >> q8;
    const int jj = jw + (it << 5) + q8;
    const short8 Es = *(const short8*)&sEj[jj];
    const short8 Fs = *(const short8*)&sEj[4096 + jj];
    const unsigned int* Eu = (const unsigned int*)&Es;
    const unsigned int* Fu = (const unsigned int*)&Fs;
    short8 af0, af1;
    MKAF(af0, sh0, Ti0, Ri0);
    MKAF(af1, sh1, Ti1, Ri1);
    #pragma unroll
    for (int c=0;c<8;++c){
      acc0[c] = __builtin_amdgcn_mfma_f32_16x16x32_bf16(af0, Bc[c], acc0[c], 0, 0, 0);
      acc1[c] = __builtin_amdgcn_mfma_f32_16x16x32_bf16(af1, Bc[c], acc1[c], 0, 0, 0);
    }
    lf0 = __builtin_amdgcn_mfma_f32_16x16x32_bf16(af0, ones8, lf0, 0, 0, 0);
    lf1 = __builtin_amdgcn_mfma_f32_16x16x32_bf16(af1, ones8, lf1, 0, 0, 0);
  }
#undef MKAF

  // cross-wave combine, two passes (rowgroup 0 then 1), reusing unioned LDS
  #pragma unroll 1
  for (int g = 0; g < 2; ++g){
    __syncthreads();
    #pragma unroll
    for (int c=0;c<8;++c){
      #pragma unroll
      for (int r=0;r<4;++r){
        const float v = g ? acc1[c][r] : acc0[c][r];
        smemc[(wave*16 + quad*4 + r)*129 + c*16 + m] = v;
      }
    }
    if (m == 0){
      #pragma unroll
      for (int r=0;r<4;++r) smemc[8256 + wave*16 + quad*4 + r] = g ? lf1[r] : lf0[r];
    }
    __syncthreads();

    #pragma unroll
    for (int k=0;k<8;++k){
      const int idx = tid + (k<<8);
      const int row = idx >> 7, col = idx & 127;
      const float s = smemc[row*129+col] + smemc[(16+row)*129+col]
                    + smemc[(32+row)*129+col] + smemc[(48+row)*129+col];
      const float l = smemc[8256+row] + smemc[8256+16+row]
                    + smemc[8256+32+row] + smemc[8256+48+row];
      float v = s / l;
      v = v > 0.f ? v : expm1f(v);             // ELU (alpha=1)
      out[((size_t)(b*GN + i0 + (g<<4) + row))*GF + col] = v;
    }
  }
}

extern "C" void kernel_launch(void* const* d_in, const int* in_sizes, int n_in,
                              void* d_out, int out_size, void* d_ws, size_t ws_size,
                              hipStream_t stream)
{
  (void)in_sizes; (void)n_in; (void)out_size; (void)ws_size;
  const float* h   = (const float*)d_in[0];
  const int*   adj = (const int*)d_in[1];
  const float* W   = (const float*)d_in[2];
  const float* a   = (const float*)d_in[3];
  float* out = (float*)d_out;

  char* ws = (char*)d_ws;
  unsigned short* whB   = (unsigned short*)ws;                    // 4 MB fragment-major
  float*          si    = (float*)(ws + (size_t)4*1024*1024);     // 64 KB
  unsigned short* EFh   = (unsigned short*)(ws + (size_t)4*1024*1024 + 64*1024);   // 64 KB

  gat_prep<<<GB*GN/16, 256, 0, stream>>>(h, W, a, whB, si, EFh);
  gat_main<<<GB*GN/32, 256, 0, stream>>>(adj, whB, si, EFh, out);
}